// Round 3
// baseline (323.350 us; speedup 1.0000x reference)
//
#include <hip/hip_runtime.h>
#include <math.h>

#ifndef M_PI
#define M_PI 3.14159265358979323846
#endif

// SPH solver step — ZERO divergent global gathers.
// Rounds 10/11 proved the divergent-gather cap: 11.6 cyc/edge per CU,
// invariant to MLP (2.7->5, null) and cache policy (nt, null). Structural.
// Round-12: two-level counting sort (j-slice 4096, i-bin 512) so both passes
// read j-data from an LDS-resident slice table and accumulate i-data in LDS.
// Every global access is coalesced; every divergent access is LDS.
// Positions quantized to u16 (err ~2e-5, better than the old f16 aux, which
// is deleted). j-side v,p stored f16 (rel 1e-3, same scale as old f16 aux).
// Reference facts exploited (unchanged):
//   * v_i - u_i == 0  -> transport stress term Ar == 0 exactly
//   * p_bg_i == 0     -> dvdt == 0 exactly (cols 5..7 written as zeros)
//   * eta_i == eta_j  -> eta_ij compile-time constant
//   * p = 100*(rho-1) -> rho recoverable from p
static constexpr float kSigma = (float)(3.0 / 359.0 / M_PI);  // H = 1
static constexpr float kPRef  = 100.0f;
static constexpr float kEps   = 1e-8f;
static constexpr float kEta   = (float)(2.0 * 0.01 * 0.01 / (0.01 + 0.01 + 1e-8));
static constexpr float kInvQ  = 1.0f / 65536.0f;

#define CH     4096   // edges per hist/split chunk
#define JS_SH  12     // j-slice = 4096 particles (LDS table)
#define JSLICE 4096
#define IB_SH  9      // i-bin = 512 particles (LDS accumulator)
#define IBSZ   512
#define C2MAX  48     // max chunks per slice (mean 32, sigma ~0.09 -> huge margin)
#define GBIN   8      // i-bins per pass block

typedef _Float16 hf4 __attribute__((ext_vector_type(4)));   // 8B {vx,vy,vz,p}

__device__ __forceinline__ float pow5f(float t) { float t2 = t * t; return t2 * t2 * t; }
__device__ __forceinline__ float pow4f(float t) { float t2 = t * t; return t2 * t2; }

__device__ __forceinline__ int nt_load_i(const int* p) { return __builtin_nontemporal_load(p); }
__device__ __forceinline__ float nt_load_f(const float* p) { return __builtin_nontemporal_load(p); }
__device__ __forceinline__ void nt_store_f(float* p, float v) { __builtin_nontemporal_store(v, p); }

__device__ __forceinline__ int scanned(const int* __restrict__ gscan,
                                       const int* __restrict__ bscan, int idx) {
    return gscan[idx] + bscan[idx >> 8];
}

// ---------------- pack positions into u16-quantized 8B records --------------
__global__ void k_pack_pos(const float* __restrict__ r, ushort4* __restrict__ posq, int n) {
    int i = blockIdx.x * blockDim.x + threadIdx.x;
    if (i >= n) return;
    float x = r[3 * i], y = r[3 * i + 1], z = r[3 * i + 2];
    ushort4 q;
    q.x = (unsigned short)fminf(x * 65536.0f, 65535.0f);
    q.y = (unsigned short)fminf(y * 65536.0f, 65535.0f);
    q.z = (unsigned short)fminf(z * 65536.0f, 65535.0f);
    q.w = 0;
    posq[i] = q;
}

// ---------------- level-1 histogram by j-slice ----------------
__global__ void k_hist1(const int* __restrict__ j_s, int* __restrict__ ghist,
                        int nbA, int nsl, int E) {
    __shared__ int h[64];
    int t = threadIdx.x, blk = blockIdx.x;
    if (t < 64) h[t] = 0;
    __syncthreads();
    int base = blk * CH;
    int end = min(base + CH, E);
    for (int kb = base; kb < end; kb += 256 * 4) {
        int jv[4];
#pragma unroll
        for (int b = 0; b < 4; b++) {
            int k = kb + b * 256 + t;
            jv[b] = (k < end) ? j_s[k] : -1;
        }
#pragma unroll
        for (int b = 0; b < 4; b++)
            if (jv[b] >= 0) atomicAdd(&h[jv[b] >> JS_SH], 1);
    }
    __syncthreads();
    if (t < nsl) ghist[t * nbA + blk] = h[t];
}

// ---------------- 2-kernel scan (verified pattern) ----------------
__global__ void k_scan_block(const int* __restrict__ in, int* __restrict__ out,
                             int* __restrict__ bsum, int m) {
    __shared__ int s[256];
    int t = threadIdx.x;
    int i = blockIdx.x * 256 + t;
    int x = (i < m) ? in[i] : 0;
    s[t] = x;
    __syncthreads();
    for (int d = 1; d < 256; d <<= 1) {
        int v = (t >= d) ? s[t - d] : 0;
        __syncthreads();
        s[t] += v;
        __syncthreads();
    }
    if (i < m) out[i] = s[t] - x;            // block-local exclusive
    if (t == 255) bsum[blockIdx.x] = s[255];
}

__global__ void k_scan_bsums(const int* __restrict__ bsum, int* __restrict__ bscan, int nb) {
    __shared__ int s[512];
    __shared__ int carry;
    int t = threadIdx.x;
    if (t == 0) carry = 0;
    __syncthreads();
    for (int base = 0; base < nb; base += 512) {
        int i = base + t;
        int x = (i < nb) ? bsum[i] : 0;
        s[t] = x;
        __syncthreads();
        for (int d = 1; d < 512; d <<= 1) {
            int v = (t >= d) ? s[t - d] : 0;
            __syncthreads();
            s[t] += v;
            __syncthreads();
        }
        if (i < nb) bscan[i] = s[t] - x + carry;
        __syncthreads();
        if (t == 511) carry += s[511];
        __syncthreads();
    }
}

// ---------------- level-1 split: bin by j-slice, payload (i<<12 | j&4095) --
__global__ void k_split1(const int* __restrict__ i_s, const int* __restrict__ j_s,
                         const int* __restrict__ ghist, const int* __restrict__ gscan,
                         const int* __restrict__ bscan, int* __restrict__ pairs1,
                         int nbA, int nsl, int E) {
    __shared__ int lofs[64];
    __shared__ int ldelta[64];
    __shared__ int stage[CH];
    __shared__ unsigned short binof[CH];
    int t = threadIdx.x, blk = blockIdx.x;
    int base = blk * CH;
    int end = min(base + CH, E);
    int cnt = end - base;

    if (t < 64) {
        int h0 = (t < nsl) ? ghist[t * nbA + blk] : 0;
        lofs[t] = h0;
    }
    __syncthreads();
    if (t == 0) {                              // tiny serial scan of <=64 bins
        int run = 0;
        for (int b = 0; b < nsl; b++) {
            int h = lofs[b];
            lofs[b] = run;                     // exclusive
            ldelta[b] = scanned(gscan, bscan, b * nbA + blk) - run;
            run += h;
        }
    }
    __syncthreads();

    for (int kb = base; kb < end; kb += 256 * 4) {
        int iv[4], jv[4];
#pragma unroll
        for (int b = 0; b < 4; b++) {
            int k = kb + b * 256 + t;
            iv[b] = (k < end) ? i_s[k] : -1;
            jv[b] = (k < end) ? j_s[k] : 0;
        }
#pragma unroll
        for (int b = 0; b < 4; b++) {
            if (iv[b] < 0) continue;
            int bin = jv[b] >> JS_SH;
            int pos = atomicAdd(&lofs[bin], 1);
            stage[pos] = (iv[b] << JS_SH) | (jv[b] & (JSLICE - 1));
            binof[pos] = (unsigned short)bin;
        }
    }
    __syncthreads();
    for (int x = t; x < cnt; x += 256)
        pairs1[x + ldelta[binof[x]]] = stage[x];
}

// ---------------- level-2 histogram: per (slice, chunk) count i-bins -------
__global__ void k_hist2(const int* __restrict__ pairs1, const int* __restrict__ gscan1,
                        const int* __restrict__ bscan1, int* __restrict__ ghist2,
                        int nbA, int nsl, int nbin, int E) {
    __shared__ int h[256];
    int t = threadIdx.x;
    int s = blockIdx.x / C2MAX, c = blockIdx.x % C2MAX;
    h[t] = 0;
    __syncthreads();
    int start = scanned(gscan1, bscan1, s * nbA);
    int end = (s + 1 < nsl) ? scanned(gscan1, bscan1, (s + 1) * nbA) : E;
    int a0 = start + c * CH, a1 = min(a0 + CH, end);
    for (int kb = a0; kb < a1; kb += 256 * 4) {
        int pv[4];
#pragma unroll
        for (int b = 0; b < 4; b++) {
            int k = kb + b * 256 + t;
            pv[b] = (k < a1) ? pairs1[k] : -1;
        }
#pragma unroll
        for (int b = 0; b < 4; b++)
            if (pv[b] >= 0) atomicAdd(&h[pv[b] >> (JS_SH + IB_SH)], 1);
    }
    __syncthreads();
    if (t < nbin) ghist2[(s * nbin + t) * C2MAX + c] = h[t];
}

// ---------------- level-2 split: per-slice bin by i-bin --------------------
__global__ void k_split2(const int* __restrict__ pairs1, const int* __restrict__ ghist2,
                         const int* __restrict__ gscan2, const int* __restrict__ bscan2,
                         const int* __restrict__ gscan1, const int* __restrict__ bscan1,
                         int* __restrict__ pairs2, int nbA, int nsl, int nbin, int E) {
    __shared__ int lofs[256];
    __shared__ int ldelta[256];
    __shared__ int stage[CH];
    __shared__ unsigned short binof[CH];
    int t = threadIdx.x;
    int s = blockIdx.x / C2MAX, c = blockIdx.x % C2MAX;
    int start = scanned(gscan1, bscan1, s * nbA);
    int end = (s + 1 < nsl) ? scanned(gscan1, bscan1, (s + 1) * nbA) : E;
    int a0 = start + c * CH, a1 = min(a0 + CH, end);
    int cnt = max(a1 - a0, 0);

    int h0 = (t < nbin) ? ghist2[(s * nbin + t) * C2MAX + c] : 0;
    lofs[t] = h0;
    __syncthreads();
    for (int d = 1; d < 256; d <<= 1) {        // inclusive scan of 256
        int v = (t >= d) ? lofs[t - d] : 0;
        __syncthreads();
        lofs[t] += v;
        __syncthreads();
    }
    int e0 = lofs[t] - h0;                     // exclusive
    __syncthreads();
    lofs[t] = e0;                              // cursor
    if (t < nbin) ldelta[t] = scanned(gscan2, bscan2, (s * nbin + t) * C2MAX + c) - e0;
    __syncthreads();

    for (int kb = a0; kb < a1; kb += 256 * 4) {
        int pv[4];
#pragma unroll
        for (int b = 0; b < 4; b++) {
            int k = kb + b * 256 + t;
            pv[b] = (k < a1) ? pairs1[k] : -1;
        }
#pragma unroll
        for (int b = 0; b < 4; b++) {
            if (pv[b] < 0) continue;
            int bin = pv[b] >> (JS_SH + IB_SH);
            int pos = atomicAdd(&lofs[bin], 1);
            stage[pos] = pv[b];
            binof[pos] = (unsigned short)bin;
        }
    }
    __syncthreads();
    for (int x = t; x < cnt; x += 256)
        pairs2[x + ldelta[binof[x]]] = stage[x];
}

// ---------------- pass 1: density — all divergence in LDS ------------------
__global__ void __launch_bounds__(256)
k_pass1(const ushort4* __restrict__ posq, const int* __restrict__ pairs2,
        const int* __restrict__ gscan2, const int* __restrict__ bscan2,
        float* __restrict__ part_rho, int n, int E, int nsl, int nbin,
        int nbg, int nk) {
    __shared__ ushort4 sjp[JSLICE];            // 32 KB
    __shared__ ushort4 sip[IBSZ];              // 4 KB
    __shared__ float srho[IBSZ];               // 2 KB
    __shared__ int sse[2];
    int t = threadIdx.x;
    int s = blockIdx.x / nbg, g = blockIdx.x % nbg;
    int j0 = s << JS_SH;
    for (int idx = t; idx < JSLICE; idx += 256) {
        int jg = j0 + idx;
        sjp[idx] = (jg < n) ? posq[jg] : make_ushort4(0, 0, 0, 0);
    }
    int b0 = g * GBIN, b1 = min(b0 + GBIN, nbin);
    for (int bin = b0; bin < b1; bin++) {
        int i0 = bin << IB_SH;
        for (int idx = t; idx < IBSZ; idx += 256) {
            int ig = i0 + idx;
            sip[idx] = (ig < n) ? posq[ig] : make_ushort4(0, 0, 0, 0);
            srho[idx] = 0.f;
        }
        if (t == 0) {
            int lin = s * nbin + bin;
            sse[0] = scanned(gscan2, bscan2, lin * C2MAX);
            sse[1] = (lin + 1 < nk) ? scanned(gscan2, bscan2, (lin + 1) * C2MAX) : E;
        }
        __syncthreads();
        int ks = sse[0], ke = sse[1];
        for (int k = ks + t; k < ke; k += 256) {
            int pr = nt_load_i(&pairs2[k]);
            int jl = pr & (JSLICE - 1);
            int il = (pr >> JS_SH) & (IBSZ - 1);
            ushort4 pj = sjp[jl];
            ushort4 pi = sip[il];
            float dx = (float)((int)pi.x - (int)pj.x) * kInvQ;
            float dy = (float)((int)pi.y - (int)pj.y) * kInvQ;
            float dz = (float)((int)pi.z - (int)pj.z) * kInvQ;
            float d = sqrtf(dx * dx + dy * dy + dz * dz);
            float t1 = fmaxf(1.f - d, 0.f);
            float t2 = fmaxf(2.f - d, 0.f);
            float t3 = fmaxf(3.f - d, 0.f);
            float w = kSigma * (pow5f(t3) - 6.f * pow5f(t2) + 15.f * pow5f(t1));
            atomicAdd(&srho[il], w);
        }
        __syncthreads();
        for (int idx = t; idx < IBSZ; idx += 256) {
            int ig = i0 + idx;
            if (ig < n) nt_store_f(&part_rho[(size_t)s * n + ig], srho[idx]);
        }
        __syncthreads();
    }
}

// ---------------- reduce rho partials; pack {v,p} f16; state out -----------
__global__ void k_reduce_rho(const float* __restrict__ part_rho,
                             const float* __restrict__ v,
                             hf4* __restrict__ vpq, float* __restrict__ out,
                             int n, int nsl) {
    int i = blockIdx.x * blockDim.x + threadIdx.x;
    if (i >= n) return;
    float rh = 0.f;
    for (int s = 0; s < nsl; s++) rh += nt_load_f(&part_rho[(size_t)s * n + i]);
    float pp = kPRef * (rh - 1.0f);
    hf4 h;
    h.x = (_Float16)v[3 * i];
    h.y = (_Float16)v[3 * i + 1];
    h.z = (_Float16)v[3 * i + 2];
    h.w = (_Float16)pp;
    vpq[i] = h;
    float* o = out + (size_t)i * 8;
    o[0] = rh;
    o[1] = pp;
    o[5] = 0.f; o[6] = 0.f; o[7] = 0.f;       // dvdt == 0 exactly
}

// ---------------- pass 2: acceleration — all divergence in LDS -------------
// dynamic LDS: sjp 32K | sjv 32K | sip 4K | siv 4K | sax 2K | say 2K | saz 2K
__global__ void __launch_bounds__(256)
k_pass2(const ushort4* __restrict__ posq, const hf4* __restrict__ vpq,
        const int* __restrict__ pairs2, const int* __restrict__ gscan2,
        const int* __restrict__ bscan2, float* __restrict__ pax,
        float* __restrict__ pay, float* __restrict__ paz,
        int n, int E, int nsl, int nbin, int nbg, int nk) {
    extern __shared__ char dyn[];
    ushort4* sjp = (ushort4*)dyn;                          // 32768
    hf4*     sjv = (hf4*)(dyn + 32768);                    // 32768
    ushort4* sip = (ushort4*)(dyn + 65536);                // 4096
    hf4*     siv = (hf4*)(dyn + 69632);                    // 4096
    float*   sax = (float*)(dyn + 73728);                  // 2048
    float*   say = (float*)(dyn + 75776);                  // 2048
    float*   saz = (float*)(dyn + 77824);                  // 2048
    __shared__ int sse[2];
    int t = threadIdx.x;
    int s = blockIdx.x / nbg, g = blockIdx.x % nbg;
    int j0 = s << JS_SH;
    for (int idx = t; idx < JSLICE; idx += 256) {
        int jg = j0 + idx;
        if (jg < n) { sjp[idx] = posq[jg]; sjv[idx] = vpq[jg]; }
        else { sjp[idx] = make_ushort4(0, 0, 0, 0); sjv[idx] = hf4{0, 0, 0, 0}; }
    }
    int b0 = g * GBIN, b1 = min(b0 + GBIN, nbin);
    for (int bin = b0; bin < b1; bin++) {
        int i0 = bin << IB_SH;
        for (int idx = t; idx < IBSZ; idx += 256) {
            int ig = i0 + idx;
            if (ig < n) { sip[idx] = posq[ig]; siv[idx] = vpq[ig]; }
            else { sip[idx] = make_ushort4(0, 0, 0, 0); siv[idx] = hf4{0, 0, 0, 0}; }
            sax[idx] = 0.f; say[idx] = 0.f; saz[idx] = 0.f;
        }
        if (t == 0) {
            int lin = s * nbin + bin;
            sse[0] = scanned(gscan2, bscan2, lin * C2MAX);
            sse[1] = (lin + 1 < nk) ? scanned(gscan2, bscan2, (lin + 1) * C2MAX) : E;
        }
        __syncthreads();
        int ks = sse[0], ke = sse[1];
        for (int k = ks + t; k < ke; k += 256) {
            int pr = nt_load_i(&pairs2[k]);
            int jl = pr & (JSLICE - 1);
            int il = (pr >> JS_SH) & (IBSZ - 1);
            ushort4 pj = sjp[jl];
            hf4 vj = sjv[jl];
            ushort4 pi = sip[il];
            hf4 vi = siv[il];
            float dx = (float)((int)pi.x - (int)pj.x) * kInvQ;
            float dy = (float)((int)pi.y - (int)pj.y) * kInvQ;
            float dz = (float)((int)pi.z - (int)pj.z) * kInvQ;
            float d = sqrtf(dx * dx + dy * dy + dz * dz);
            float p_i = (float)vi.w, p_j = (float)vj.w;
            float rho_i = p_i * 0.01f + 1.0f;
            float rho_j = p_j * 0.01f + 1.0f;
            float t1 = fmaxf(1.f - d, 0.f);
            float t2 = fmaxf(2.f - d, 0.f);
            float t3 = fmaxf(3.f - d, 0.f);
            float gw = kSigma * (-5.f * pow4f(t3) + 30.f * pow4f(t2) - 75.f * pow4f(t1));
            float inv_i = 1.0f / rho_i, inv_j = 1.0f / rho_j;
            float c = (inv_i * inv_i + inv_j * inv_j) * gw / (d + kEps);
            float p_ij = (rho_j * p_i + rho_i * p_j) / (rho_i + rho_j);
            atomicAdd(&sax[il], c * (kEta * ((float)vi.x - (float)vj.x) - p_ij * dx));
            atomicAdd(&say[il], c * (kEta * ((float)vi.y - (float)vj.y) - p_ij * dy));
            atomicAdd(&saz[il], c * (kEta * ((float)vi.z - (float)vj.z) - p_ij * dz));
        }
        __syncthreads();
        for (int idx = t; idx < IBSZ; idx += 256) {
            int ig = i0 + idx;
            if (ig < n) {
                nt_store_f(&pax[(size_t)s * n + ig], sax[idx]);
                nt_store_f(&pay[(size_t)s * n + ig], say[idx]);
                nt_store_f(&paz[(size_t)s * n + ig], saz[idx]);
            }
        }
        __syncthreads();
    }
}

// ---------------- reduce acc partials ----------------
__global__ void k_reduce_acc(const float* __restrict__ pax, const float* __restrict__ pay,
                             const float* __restrict__ paz, float* __restrict__ out,
                             int n, int nsl) {
    int i = blockIdx.x * blockDim.x + threadIdx.x;
    if (i >= n) return;
    float ax = 0.f, ay = 0.f, az = 0.f;
    for (int s = 0; s < nsl; s++) {
        ax += nt_load_f(&pax[(size_t)s * n + i]);
        ay += nt_load_f(&pay[(size_t)s * n + i]);
        az += nt_load_f(&paz[(size_t)s * n + i]);
    }
    float* o = out + (size_t)i * 8 + 2;
    o[0] = ax; o[1] = ay; o[2] = az;
}

// ---------------- launch ----------------
static inline char* wcarve(char*& ws, size_t bytes) {
    char* p = ws;
    ws += (bytes + 255) & ~(size_t)255;
    return p;
}

extern "C" void kernel_launch(void* const* d_in, const int* in_sizes, int n_in,
                              void* d_out, int out_size, void* d_ws, size_t ws_size,
                              hipStream_t stream) {
    const float* r = (const float*)d_in[0];
    const float* v = (const float*)d_in[1];
    const int* i_s = (const int*)d_in[2];
    const int* j_s = (const int*)d_in[3];
    int n = in_sizes[0] / 3;
    int E = in_sizes[2];
    float* out = (float*)d_out;

    int nsl  = ((n - 1) >> JS_SH) + 1;                 // 25 j-slices
    int nbin = ((n - 1) >> IB_SH) + 1;                 // 196 i-bins
    int nk   = nsl * nbin;                             // 4900 keys
    int nbg  = (nbin + GBIN - 1) / GBIN;               // 25 bin-groups
    int nbA  = (E + CH - 1) / CH;                      // 782 chunks
    int m1   = nsl * nbA;                              // level-1 scan length
    int m2   = nk * C2MAX;                             // level-2 scan length
    int nb1  = (m1 + 255) / 256;
    int nb2  = (m2 + 255) / 256;

    char* ws = (char*)d_ws;
    ushort4* posq   = (ushort4*)wcarve(ws, (size_t)n * 8);
    hf4*     vpq    = (hf4*)wcarve(ws, (size_t)n * 8);
    int*     ghist1 = (int*)wcarve(ws, (size_t)m1 * 4);
    int*     gscan1 = (int*)wcarve(ws, (size_t)m1 * 4);
    int*     bsum1  = (int*)wcarve(ws, (size_t)nb1 * 4);
    int*     bscan1 = (int*)wcarve(ws, (size_t)nb1 * 4);
    int*     pairs1 = (int*)wcarve(ws, (size_t)E * 4);
    int*     ghist2 = (int*)wcarve(ws, (size_t)m2 * 4);
    int*     gscan2 = (int*)wcarve(ws, (size_t)m2 * 4);
    int*     bsum2  = (int*)wcarve(ws, (size_t)nb2 * 4);
    int*     bscan2 = (int*)wcarve(ws, (size_t)nb2 * 4);
    int*     pairs2 = (int*)wcarve(ws, (size_t)E * 4);
    float*   part_rho = (float*)wcarve(ws, (size_t)nsl * n * 4);
    float*   pax    = (float*)wcarve(ws, (size_t)nsl * n * 4);
    float*   pay    = (float*)wcarve(ws, (size_t)nsl * n * 4);
    float*   paz    = (float*)wcarve(ws, (size_t)nsl * n * 4);

    const int bs = 256;
    int gn = (n + bs - 1) / bs;

    static bool attr_set = false;
    if (!attr_set) {
        hipFuncSetAttribute((const void*)k_pass2,
                            hipFuncAttributeMaxDynamicSharedMemorySize, 81920);
        attr_set = true;
    }

    k_pack_pos<<<gn, bs, 0, stream>>>(r, posq, n);
    k_hist1<<<nbA, 256, 0, stream>>>(j_s, ghist1, nbA, nsl, E);
    k_scan_block<<<nb1, 256, 0, stream>>>(ghist1, gscan1, bsum1, m1);
    k_scan_bsums<<<1, 512, 0, stream>>>(bsum1, bscan1, nb1);
    k_split1<<<nbA, 256, 0, stream>>>(i_s, j_s, ghist1, gscan1, bscan1, pairs1, nbA, nsl, E);
    k_hist2<<<nsl * C2MAX, 256, 0, stream>>>(pairs1, gscan1, bscan1, ghist2, nbA, nsl, nbin, E);
    k_scan_block<<<nb2, 256, 0, stream>>>(ghist2, gscan2, bsum2, m2);
    k_scan_bsums<<<1, 512, 0, stream>>>(bsum2, bscan2, nb2);
    k_split2<<<nsl * C2MAX, 256, 0, stream>>>(pairs1, ghist2, gscan2, bscan2,
                                              gscan1, bscan1, pairs2, nbA, nsl, nbin, E);
    k_pass1<<<nsl * nbg, 256, 0, stream>>>(posq, pairs2, gscan2, bscan2, part_rho,
                                           n, E, nsl, nbin, nbg, nk);
    k_reduce_rho<<<gn, bs, 0, stream>>>(part_rho, v, vpq, out, n, nsl);
    k_pass2<<<nsl * nbg, 256, 81920, stream>>>(posq, vpq, pairs2, gscan2, bscan2,
                                               pax, pay, paz, n, E, nsl, nbin, nbg, nk);
    k_reduce_acc<<<gn, bs, 0, stream>>>(pax, pay, paz, out, n, nsl);
}

// Round 4
// 297.006 us; speedup vs baseline: 1.0887x; 1.0887x over previous
//
#include <hip/hip_runtime.h>
#include <math.h>

#ifndef M_PI
#define M_PI 3.14159265358979323846
#endif

// SPH solver step — ZERO divergent global gathers (two-level counting sort).
// Round-12 post-mortem: structure right, occupancy wrong — 82KB LDS @256thr
// -> 1 block/CU = 4 waves/CU = latency-bound (Occupancy 9%, VALU 10%).
// Round-13: 512-thread pass blocks; pass2 dyn-LDS trimmed to 79872B so
// TWO blocks/CU fit (16 waves/CU); pass1 38.9KB static -> 4 blocks/CU
// (32 waves/CU, launch_bounds(512,8) caps VGPR at 64); batch-4 masked
// inner loop for 4x ILP on LDS reads. No algorithm change.
// Reference facts exploited (unchanged):
//   * v_i - u_i == 0  -> transport stress term Ar == 0 exactly
//   * p_bg_i == 0     -> dvdt == 0 exactly (cols 5..7 written as zeros)
//   * eta_i == eta_j  -> eta_ij compile-time constant
//   * p = 100*(rho-1) -> rho recoverable from p
static constexpr float kSigma = (float)(3.0 / 359.0 / M_PI);  // H = 1
static constexpr float kPRef  = 100.0f;
static constexpr float kEps   = 1e-8f;
static constexpr float kEta   = (float)(2.0 * 0.01 * 0.01 / (0.01 + 0.01 + 1e-8));
static constexpr float kInvQ  = 1.0f / 65536.0f;

#define CH     4096   // edges per hist/split chunk
#define JS_SH  12     // j-slice = 4096 particles (LDS table)
#define JSLICE 4096
#define IB_SH  9      // i-bin = 512 particles (LDS accumulator)
#define IBSZ   512
#define C2MAX  48     // max chunks per slice (mean 32, sigma tiny)
#define GBIN   8      // i-bins per pass block
#define PB     512    // pass-kernel block size (8 waves)

typedef _Float16 hf4 __attribute__((ext_vector_type(4)));   // 8B {vx,vy,vz,p}

__device__ __forceinline__ float pow5f(float t) { float t2 = t * t; return t2 * t2 * t; }
__device__ __forceinline__ float pow4f(float t) { float t2 = t * t; return t2 * t2; }

__device__ __forceinline__ int nt_load_i(const int* p) { return __builtin_nontemporal_load(p); }
__device__ __forceinline__ float nt_load_f(const float* p) { return __builtin_nontemporal_load(p); }
__device__ __forceinline__ void nt_store_f(float* p, float v) { __builtin_nontemporal_store(v, p); }

__device__ __forceinline__ int scanned(const int* __restrict__ gscan,
                                       const int* __restrict__ bscan, int idx) {
    return gscan[idx] + bscan[idx >> 8];
}

// ---------------- pack positions into u16-quantized 8B records --------------
__global__ void k_pack_pos(const float* __restrict__ r, ushort4* __restrict__ posq, int n) {
    int i = blockIdx.x * blockDim.x + threadIdx.x;
    if (i >= n) return;
    float x = r[3 * i], y = r[3 * i + 1], z = r[3 * i + 2];
    ushort4 q;
    q.x = (unsigned short)fminf(x * 65536.0f, 65535.0f);
    q.y = (unsigned short)fminf(y * 65536.0f, 65535.0f);
    q.z = (unsigned short)fminf(z * 65536.0f, 65535.0f);
    q.w = 0;
    posq[i] = q;
}

// ---------------- level-1 histogram by j-slice ----------------
__global__ void k_hist1(const int* __restrict__ j_s, int* __restrict__ ghist,
                        int nbA, int nsl, int E) {
    __shared__ int h[64];
    int t = threadIdx.x, blk = blockIdx.x;
    if (t < 64) h[t] = 0;
    __syncthreads();
    int base = blk * CH;
    int end = min(base + CH, E);
    for (int kb = base; kb < end; kb += 256 * 4) {
        int jv[4];
#pragma unroll
        for (int b = 0; b < 4; b++) {
            int k = kb + b * 256 + t;
            jv[b] = (k < end) ? j_s[k] : -1;
        }
#pragma unroll
        for (int b = 0; b < 4; b++)
            if (jv[b] >= 0) atomicAdd(&h[jv[b] >> JS_SH], 1);
    }
    __syncthreads();
    if (t < nsl) ghist[t * nbA + blk] = h[t];
}

// ---------------- 2-kernel scan (verified pattern) ----------------
__global__ void k_scan_block(const int* __restrict__ in, int* __restrict__ out,
                             int* __restrict__ bsum, int m) {
    __shared__ int s[256];
    int t = threadIdx.x;
    int i = blockIdx.x * 256 + t;
    int x = (i < m) ? in[i] : 0;
    s[t] = x;
    __syncthreads();
    for (int d = 1; d < 256; d <<= 1) {
        int v = (t >= d) ? s[t - d] : 0;
        __syncthreads();
        s[t] += v;
        __syncthreads();
    }
    if (i < m) out[i] = s[t] - x;            // block-local exclusive
    if (t == 255) bsum[blockIdx.x] = s[255];
}

__global__ void k_scan_bsums(const int* __restrict__ bsum, int* __restrict__ bscan, int nb) {
    __shared__ int s[512];
    __shared__ int carry;
    int t = threadIdx.x;
    if (t == 0) carry = 0;
    __syncthreads();
    for (int base = 0; base < nb; base += 512) {
        int i = base + t;
        int x = (i < nb) ? bsum[i] : 0;
        s[t] = x;
        __syncthreads();
        for (int d = 1; d < 512; d <<= 1) {
            int v = (t >= d) ? s[t - d] : 0;
            __syncthreads();
            s[t] += v;
            __syncthreads();
        }
        if (i < nb) bscan[i] = s[t] - x + carry;
        __syncthreads();
        if (t == 511) carry += s[511];
        __syncthreads();
    }
}

// ---------------- level-1 split: bin by j-slice, payload (i<<12 | j&4095) --
__global__ void k_split1(const int* __restrict__ i_s, const int* __restrict__ j_s,
                         const int* __restrict__ ghist, const int* __restrict__ gscan,
                         const int* __restrict__ bscan, int* __restrict__ pairs1,
                         int nbA, int nsl, int E) {
    __shared__ int lofs[64];
    __shared__ int ldelta[64];
    __shared__ int stage[CH];
    __shared__ unsigned short binof[CH];
    int t = threadIdx.x, blk = blockIdx.x;
    int base = blk * CH;
    int end = min(base + CH, E);
    int cnt = end - base;

    if (t < 64) {
        int h0 = (t < nsl) ? ghist[t * nbA + blk] : 0;
        lofs[t] = h0;
    }
    __syncthreads();
    if (t == 0) {                              // tiny serial scan of <=64 bins
        int run = 0;
        for (int b = 0; b < nsl; b++) {
            int h = lofs[b];
            lofs[b] = run;                     // exclusive
            ldelta[b] = scanned(gscan, bscan, b * nbA + blk) - run;
            run += h;
        }
    }
    __syncthreads();

    for (int kb = base; kb < end; kb += 256 * 4) {
        int iv[4], jv[4];
#pragma unroll
        for (int b = 0; b < 4; b++) {
            int k = kb + b * 256 + t;
            iv[b] = (k < end) ? i_s[k] : -1;
            jv[b] = (k < end) ? j_s[k] : 0;
        }
#pragma unroll
        for (int b = 0; b < 4; b++) {
            if (iv[b] < 0) continue;
            int bin = jv[b] >> JS_SH;
            int pos = atomicAdd(&lofs[bin], 1);
            stage[pos] = (iv[b] << JS_SH) | (jv[b] & (JSLICE - 1));
            binof[pos] = (unsigned short)bin;
        }
    }
    __syncthreads();
    for (int x = t; x < cnt; x += 256)
        pairs1[x + ldelta[binof[x]]] = stage[x];
}

// ---------------- level-2 histogram: per (slice, chunk) count i-bins -------
__global__ void k_hist2(const int* __restrict__ pairs1, const int* __restrict__ gscan1,
                        const int* __restrict__ bscan1, int* __restrict__ ghist2,
                        int nbA, int nsl, int nbin, int E) {
    __shared__ int h[256];
    int t = threadIdx.x;
    int s = blockIdx.x / C2MAX, c = blockIdx.x % C2MAX;
    h[t] = 0;
    __syncthreads();
    int start = scanned(gscan1, bscan1, s * nbA);
    int end = (s + 1 < nsl) ? scanned(gscan1, bscan1, (s + 1) * nbA) : E;
    int a0 = start + c * CH, a1 = min(a0 + CH, end);
    for (int kb = a0; kb < a1; kb += 256 * 4) {
        int pv[4];
#pragma unroll
        for (int b = 0; b < 4; b++) {
            int k = kb + b * 256 + t;
            pv[b] = (k < a1) ? pairs1[k] : -1;
        }
#pragma unroll
        for (int b = 0; b < 4; b++)
            if (pv[b] >= 0) atomicAdd(&h[pv[b] >> (JS_SH + IB_SH)], 1);
    }
    __syncthreads();
    if (t < nbin) ghist2[(s * nbin + t) * C2MAX + c] = h[t];
}

// ---------------- level-2 split: per-slice bin by i-bin --------------------
__global__ void k_split2(const int* __restrict__ pairs1, const int* __restrict__ ghist2,
                         const int* __restrict__ gscan2, const int* __restrict__ bscan2,
                         const int* __restrict__ gscan1, const int* __restrict__ bscan1,
                         int* __restrict__ pairs2, int nbA, int nsl, int nbin, int E) {
    __shared__ int lofs[256];
    __shared__ int ldelta[256];
    __shared__ int stage[CH];
    __shared__ unsigned short binof[CH];
    int t = threadIdx.x;
    int s = blockIdx.x / C2MAX, c = blockIdx.x % C2MAX;
    int start = scanned(gscan1, bscan1, s * nbA);
    int end = (s + 1 < nsl) ? scanned(gscan1, bscan1, (s + 1) * nbA) : E;
    int a0 = start + c * CH, a1 = min(a0 + CH, end);
    int cnt = max(a1 - a0, 0);

    int h0 = (t < nbin) ? ghist2[(s * nbin + t) * C2MAX + c] : 0;
    lofs[t] = h0;
    __syncthreads();
    for (int d = 1; d < 256; d <<= 1) {        // inclusive scan of 256
        int v = (t >= d) ? lofs[t - d] : 0;
        __syncthreads();
        lofs[t] += v;
        __syncthreads();
    }
    int e0 = lofs[t] - h0;                     // exclusive
    __syncthreads();
    lofs[t] = e0;                              // cursor
    if (t < nbin) ldelta[t] = scanned(gscan2, bscan2, (s * nbin + t) * C2MAX + c) - e0;
    __syncthreads();

    for (int kb = a0; kb < a1; kb += 256 * 4) {
        int pv[4];
#pragma unroll
        for (int b = 0; b < 4; b++) {
            int k = kb + b * 256 + t;
            pv[b] = (k < a1) ? pairs1[k] : -1;
        }
#pragma unroll
        for (int b = 0; b < 4; b++) {
            if (pv[b] < 0) continue;
            int bin = pv[b] >> (JS_SH + IB_SH);
            int pos = atomicAdd(&lofs[bin], 1);
            stage[pos] = pv[b];
            binof[pos] = (unsigned short)bin;
        }
    }
    __syncthreads();
    for (int x = t; x < cnt; x += 256)
        pairs2[x + ldelta[binof[x]]] = stage[x];
}

// ---------------- pass 1: density — 512 thr, 4 blocks/CU, batch-4 ----------
__global__ void __launch_bounds__(PB, 8)
k_pass1(const ushort4* __restrict__ posq, const int* __restrict__ pairs2,
        const int* __restrict__ gscan2, const int* __restrict__ bscan2,
        float* __restrict__ part_rho, int n, int E, int nsl, int nbin,
        int nbg, int nk) {
    __shared__ ushort4 sjp[JSLICE];            // 32 KB
    __shared__ ushort4 sip[IBSZ];              // 4 KB
    __shared__ float srho[IBSZ];               // 2 KB
    __shared__ int sse[2];
    int t = threadIdx.x;
    int s = blockIdx.x / nbg, g = blockIdx.x % nbg;
    int j0 = s << JS_SH;
    for (int idx = t; idx < JSLICE; idx += PB) {
        int jg = j0 + idx;
        sjp[idx] = (jg < n) ? posq[jg] : make_ushort4(0, 0, 0, 0);
    }
    int b0 = g * GBIN, b1 = min(b0 + GBIN, nbin);
    for (int bin = b0; bin < b1; bin++) {
        int i0 = bin << IB_SH;
        if (t < IBSZ) {
            int ig = i0 + t;
            sip[t] = (ig < n) ? posq[ig] : make_ushort4(0, 0, 0, 0);
            srho[t] = 0.f;
        }
        if (t == 0) {
            int lin = s * nbin + bin;
            sse[0] = scanned(gscan2, bscan2, lin * C2MAX);
            sse[1] = (lin + 1 < nk) ? scanned(gscan2, bscan2, (lin + 1) * C2MAX) : E;
        }
        __syncthreads();
        int ks = sse[0], ke = sse[1];
        for (int kb = ks; kb < ke; kb += PB * 4) {
            int pr[4];
            bool live[4];
#pragma unroll
            for (int b = 0; b < 4; b++) {
                int k = kb + b * PB + t;
                live[b] = (k < ke);
                pr[b] = nt_load_i(&pairs2[live[b] ? k : ke - 1]);
            }
            ushort4 pj[4], pi[4];
#pragma unroll
            for (int b = 0; b < 4; b++) {
                pj[b] = sjp[pr[b] & (JSLICE - 1)];
                pi[b] = sip[(pr[b] >> JS_SH) & (IBSZ - 1)];
            }
#pragma unroll
            for (int b = 0; b < 4; b++) {
                float dx = (float)((int)pi[b].x - (int)pj[b].x) * kInvQ;
                float dy = (float)((int)pi[b].y - (int)pj[b].y) * kInvQ;
                float dz = (float)((int)pi[b].z - (int)pj[b].z) * kInvQ;
                float d = sqrtf(dx * dx + dy * dy + dz * dz);
                float t1 = fmaxf(1.f - d, 0.f);
                float t2 = fmaxf(2.f - d, 0.f);
                float t3 = fmaxf(3.f - d, 0.f);
                float w = kSigma * (pow5f(t3) - 6.f * pow5f(t2) + 15.f * pow5f(t1));
                if (live[b]) atomicAdd(&srho[(pr[b] >> JS_SH) & (IBSZ - 1)], w);
            }
        }
        __syncthreads();
        if (t < IBSZ) {
            int ig = i0 + t;
            if (ig < n) nt_store_f(&part_rho[(size_t)s * n + ig], srho[t]);
        }
        __syncthreads();
    }
}

// ---------------- reduce rho partials; pack {v,p} f16; state out -----------
__global__ void k_reduce_rho(const float* __restrict__ part_rho,
                             const float* __restrict__ v,
                             hf4* __restrict__ vpq, float* __restrict__ out,
                             int n, int nsl) {
    int i = blockIdx.x * blockDim.x + threadIdx.x;
    if (i >= n) return;
    float rh = 0.f;
    for (int s = 0; s < nsl; s++) rh += nt_load_f(&part_rho[(size_t)s * n + i]);
    float pp = kPRef * (rh - 1.0f);
    hf4 h;
    h.x = (_Float16)v[3 * i];
    h.y = (_Float16)v[3 * i + 1];
    h.z = (_Float16)v[3 * i + 2];
    h.w = (_Float16)pp;
    vpq[i] = h;
    float* o = out + (size_t)i * 8;
    o[0] = rh;
    o[1] = pp;
    o[5] = 0.f; o[6] = 0.f; o[7] = 0.f;       // dvdt == 0 exactly
}

// ---------------- pass 2: acceleration — 512 thr, 2 blocks/CU, batch-4 -----
// dynamic LDS (79872B): sjp 32K | sjv 32K | sip 4K | siv 4K | sax/say/saz 6K
__global__ void __launch_bounds__(PB, 4)
k_pass2(const ushort4* __restrict__ posq, const hf4* __restrict__ vpq,
        const int* __restrict__ pairs2, const int* __restrict__ gscan2,
        const int* __restrict__ bscan2, float* __restrict__ pax,
        float* __restrict__ pay, float* __restrict__ paz,
        int n, int E, int nsl, int nbin, int nbg, int nk) {
    extern __shared__ char dyn[];
    ushort4* sjp = (ushort4*)dyn;                          // 32768
    hf4*     sjv = (hf4*)(dyn + 32768);                    // 32768
    ushort4* sip = (ushort4*)(dyn + 65536);                // 4096
    hf4*     siv = (hf4*)(dyn + 69632);                    // 4096
    float*   sax = (float*)(dyn + 73728);                  // 2048
    float*   say = (float*)(dyn + 75776);                  // 2048
    float*   saz = (float*)(dyn + 77824);                  // 2048
    __shared__ int sse[2];
    int t = threadIdx.x;
    int s = blockIdx.x / nbg, g = blockIdx.x % nbg;
    int j0 = s << JS_SH;
    for (int idx = t; idx < JSLICE; idx += PB) {
        int jg = j0 + idx;
        if (jg < n) { sjp[idx] = posq[jg]; sjv[idx] = vpq[jg]; }
        else { sjp[idx] = make_ushort4(0, 0, 0, 0); sjv[idx] = hf4{0, 0, 0, 0}; }
    }
    int b0 = g * GBIN, b1 = min(b0 + GBIN, nbin);
    for (int bin = b0; bin < b1; bin++) {
        int i0 = bin << IB_SH;
        if (t < IBSZ) {
            int ig = i0 + t;
            if (ig < n) { sip[t] = posq[ig]; siv[t] = vpq[ig]; }
            else { sip[t] = make_ushort4(0, 0, 0, 0); siv[t] = hf4{0, 0, 0, 0}; }
            sax[t] = 0.f; say[t] = 0.f; saz[t] = 0.f;
        }
        if (t == 0) {
            int lin = s * nbin + bin;
            sse[0] = scanned(gscan2, bscan2, lin * C2MAX);
            sse[1] = (lin + 1 < nk) ? scanned(gscan2, bscan2, (lin + 1) * C2MAX) : E;
        }
        __syncthreads();
        int ks = sse[0], ke = sse[1];
        for (int kb = ks; kb < ke; kb += PB * 4) {
            int pr[4];
            bool live[4];
#pragma unroll
            for (int b = 0; b < 4; b++) {
                int k = kb + b * PB + t;
                live[b] = (k < ke);
                pr[b] = nt_load_i(&pairs2[live[b] ? k : ke - 1]);
            }
            ushort4 pj[4], pi[4];
            hf4 vj[4], vi[4];
#pragma unroll
            for (int b = 0; b < 4; b++) {
                int jl = pr[b] & (JSLICE - 1);
                int il = (pr[b] >> JS_SH) & (IBSZ - 1);
                pj[b] = sjp[jl];
                vj[b] = sjv[jl];
                pi[b] = sip[il];
                vi[b] = siv[il];
            }
#pragma unroll
            for (int b = 0; b < 4; b++) {
                int il = (pr[b] >> JS_SH) & (IBSZ - 1);
                float dx = (float)((int)pi[b].x - (int)pj[b].x) * kInvQ;
                float dy = (float)((int)pi[b].y - (int)pj[b].y) * kInvQ;
                float dz = (float)((int)pi[b].z - (int)pj[b].z) * kInvQ;
                float d = sqrtf(dx * dx + dy * dy + dz * dz);
                float p_i = (float)vi[b].w, p_j = (float)vj[b].w;
                float rho_i = p_i * 0.01f + 1.0f;
                float rho_j = p_j * 0.01f + 1.0f;
                float t1 = fmaxf(1.f - d, 0.f);
                float t2 = fmaxf(2.f - d, 0.f);
                float t3 = fmaxf(3.f - d, 0.f);
                float gw = kSigma * (-5.f * pow4f(t3) + 30.f * pow4f(t2) - 75.f * pow4f(t1));
                float inv_i = 1.0f / rho_i, inv_j = 1.0f / rho_j;
                float c = (inv_i * inv_i + inv_j * inv_j) * gw / (d + kEps);
                float p_ij = (rho_j * p_i + rho_i * p_j) / (rho_i + rho_j);
                if (live[b]) {
                    atomicAdd(&sax[il], c * (kEta * ((float)vi[b].x - (float)vj[b].x) - p_ij * dx));
                    atomicAdd(&say[il], c * (kEta * ((float)vi[b].y - (float)vj[b].y) - p_ij * dy));
                    atomicAdd(&saz[il], c * (kEta * ((float)vi[b].z - (float)vj[b].z) - p_ij * dz));
                }
            }
        }
        __syncthreads();
        if (t < IBSZ) {
            int ig = i0 + t;
            if (ig < n) {
                nt_store_f(&pax[(size_t)s * n + ig], sax[t]);
                nt_store_f(&pay[(size_t)s * n + ig], say[t]);
                nt_store_f(&paz[(size_t)s * n + ig], saz[t]);
            }
        }
        __syncthreads();
    }
}

// ---------------- reduce acc partials ----------------
__global__ void k_reduce_acc(const float* __restrict__ pax, const float* __restrict__ pay,
                             const float* __restrict__ paz, float* __restrict__ out,
                             int n, int nsl) {
    int i = blockIdx.x * blockDim.x + threadIdx.x;
    if (i >= n) return;
    float ax = 0.f, ay = 0.f, az = 0.f;
    for (int s = 0; s < nsl; s++) {
        ax += nt_load_f(&pax[(size_t)s * n + i]);
        ay += nt_load_f(&pay[(size_t)s * n + i]);
        az += nt_load_f(&paz[(size_t)s * n + i]);
    }
    float* o = out + (size_t)i * 8 + 2;
    o[0] = ax; o[1] = ay; o[2] = az;
}

// ---------------- launch ----------------
static inline char* wcarve(char*& ws, size_t bytes) {
    char* p = ws;
    ws += (bytes + 255) & ~(size_t)255;
    return p;
}

extern "C" void kernel_launch(void* const* d_in, const int* in_sizes, int n_in,
                              void* d_out, int out_size, void* d_ws, size_t ws_size,
                              hipStream_t stream) {
    const float* r = (const float*)d_in[0];
    const float* v = (const float*)d_in[1];
    const int* i_s = (const int*)d_in[2];
    const int* j_s = (const int*)d_in[3];
    int n = in_sizes[0] / 3;
    int E = in_sizes[2];
    float* out = (float*)d_out;

    int nsl  = ((n - 1) >> JS_SH) + 1;                 // 25 j-slices
    int nbin = ((n - 1) >> IB_SH) + 1;                 // 196 i-bins
    int nk   = nsl * nbin;                             // 4900 keys
    int nbg  = (nbin + GBIN - 1) / GBIN;               // 25 bin-groups
    int nbA  = (E + CH - 1) / CH;                      // 782 chunks
    int m1   = nsl * nbA;                              // level-1 scan length
    int m2   = nk * C2MAX;                             // level-2 scan length
    int nb1  = (m1 + 255) / 256;
    int nb2  = (m2 + 255) / 256;

    char* ws = (char*)d_ws;
    ushort4* posq   = (ushort4*)wcarve(ws, (size_t)n * 8);
    hf4*     vpq    = (hf4*)wcarve(ws, (size_t)n * 8);
    int*     ghist1 = (int*)wcarve(ws, (size_t)m1 * 4);
    int*     gscan1 = (int*)wcarve(ws, (size_t)m1 * 4);
    int*     bsum1  = (int*)wcarve(ws, (size_t)nb1 * 4);
    int*     bscan1 = (int*)wcarve(ws, (size_t)nb1 * 4);
    int*     pairs1 = (int*)wcarve(ws, (size_t)E * 4);
    int*     ghist2 = (int*)wcarve(ws, (size_t)m2 * 4);
    int*     gscan2 = (int*)wcarve(ws, (size_t)m2 * 4);
    int*     bsum2  = (int*)wcarve(ws, (size_t)nb2 * 4);
    int*     bscan2 = (int*)wcarve(ws, (size_t)nb2 * 4);
    int*     pairs2 = (int*)wcarve(ws, (size_t)E * 4);
    float*   part_rho = (float*)wcarve(ws, (size_t)nsl * n * 4);
    float*   pax    = (float*)wcarve(ws, (size_t)nsl * n * 4);
    float*   pay    = (float*)wcarve(ws, (size_t)nsl * n * 4);
    float*   paz    = (float*)wcarve(ws, (size_t)nsl * n * 4);

    const int bs = 256;
    int gn = (n + bs - 1) / bs;

    static bool attr_set = false;
    if (!attr_set) {
        hipFuncSetAttribute((const void*)k_pass2,
                            hipFuncAttributeMaxDynamicSharedMemorySize, 79872);
        attr_set = true;
    }

    k_pack_pos<<<gn, bs, 0, stream>>>(r, posq, n);
    k_hist1<<<nbA, 256, 0, stream>>>(j_s, ghist1, nbA, nsl, E);
    k_scan_block<<<nb1, 256, 0, stream>>>(ghist1, gscan1, bsum1, m1);
    k_scan_bsums<<<1, 512, 0, stream>>>(bsum1, bscan1, nb1);
    k_split1<<<nbA, 256, 0, stream>>>(i_s, j_s, ghist1, gscan1, bscan1, pairs1, nbA, nsl, E);
    k_hist2<<<nsl * C2MAX, 256, 0, stream>>>(pairs1, gscan1, bscan1, ghist2, nbA, nsl, nbin, E);
    k_scan_block<<<nb2, 256, 0, stream>>>(ghist2, gscan2, bsum2, m2);
    k_scan_bsums<<<1, 512, 0, stream>>>(bsum2, bscan2, nb2);
    k_split2<<<nsl * C2MAX, 256, 0, stream>>>(pairs1, ghist2, gscan2, bscan2,
                                              gscan1, bscan1, pairs2, nbA, nsl, nbin, E);
    k_pass1<<<nsl * nbg, PB, 0, stream>>>(posq, pairs2, gscan2, bscan2, part_rho,
                                          n, E, nsl, nbin, nbg, nk);
    k_reduce_rho<<<gn, bs, 0, stream>>>(part_rho, v, vpq, out, n, nsl);
    k_pass2<<<nsl * nbg, PB, 79872, stream>>>(posq, vpq, pairs2, gscan2, bscan2,
                                              pax, pay, paz, n, E, nsl, nbin, nbg, nk);
    k_reduce_acc<<<gn, bs, 0, stream>>>(pax, pay, paz, out, n, nsl);
}

// Round 5
// 262.219 us; speedup vs baseline: 1.2331x; 1.1327x over previous
//
#include <hip/hip_runtime.h>
#include <math.h>

#ifndef M_PI
#define M_PI 3.14159265358979323846
#endif

// SPH solver step — ZERO divergent global gathers (two-level counting sort).
// Round-13 post-mortem: 80KB dyn-LDS -> still 1 block/CU (26.7% occ); per-bin
// serial {scanned() x2, stage, bar, 1 iter, bar, writeout} chains exposed
// ~10 global latencies per bin with nothing to overlap. VALUBusy 12%.
// Round-14: LDS diet so MULTIPLE blocks co-reside and overlap each other's
// barrier chains:
//   * pass1 re-emits f16 aux{dx,dy,dz,d} (proven r<=11 precision) so pass2
//     needs NO positions: sjv 32K + siv 4K + acc 6K = 43KB -> 3 blocks/CU.
//   * pass1: sjp 32K + sip 4K + srho 2K = 39KB -> 4 blocks/CU (32 waves).
//   * per-block bin ranges precomputed by 9 parallel threads (kills 8x
//     serial single-lane scanned() round trips).
//   * batch-2 masked inner loop (1024 slots >= worst bin ~800).
// Reference facts exploited (unchanged):
//   * v_i - u_i == 0  -> transport stress term Ar == 0 exactly
//   * p_bg_i == 0     -> dvdt == 0 exactly (cols 5..7 written as zeros)
//   * eta_i == eta_j  -> eta_ij compile-time constant
//   * p = 100*(rho-1) -> rho recoverable from p
static constexpr float kSigma = (float)(3.0 / 359.0 / M_PI);  // H = 1
static constexpr float kPRef  = 100.0f;
static constexpr float kEps   = 1e-8f;
static constexpr float kEta   = (float)(2.0 * 0.01 * 0.01 / (0.01 + 0.01 + 1e-8));
static constexpr float kInvQ  = 1.0f / 65536.0f;

#define CH     4096   // edges per hist/split chunk
#define JS_SH  12     // j-slice = 4096 particles (LDS table)
#define JSLICE 4096
#define IB_SH  9      // i-bin = 512 particles (LDS accumulator)
#define IBSZ   512
#define C2MAX  48     // max chunks per slice (mean 32, sigma tiny)
#define GBIN   8      // i-bins per pass block
#define PB     512    // pass-kernel block size (8 waves)

typedef _Float16 hf4 __attribute__((ext_vector_type(4)));   // 8B records

__device__ __forceinline__ float pow5f(float t) { float t2 = t * t; return t2 * t2 * t; }
__device__ __forceinline__ float pow4f(float t) { float t2 = t * t; return t2 * t2; }

__device__ __forceinline__ int nt_load_i(const int* p) { return __builtin_nontemporal_load(p); }
__device__ __forceinline__ hf4 nt_load_h4(const hf4* p) { return __builtin_nontemporal_load(p); }
__device__ __forceinline__ void nt_store_h4(hf4* p, hf4 v) { __builtin_nontemporal_store(v, p); }
__device__ __forceinline__ float nt_load_f(const float* p) { return __builtin_nontemporal_load(p); }
__device__ __forceinline__ void nt_store_f(float* p, float v) { __builtin_nontemporal_store(v, p); }

__device__ __forceinline__ int scanned(const int* __restrict__ gscan,
                                       const int* __restrict__ bscan, int idx) {
    return gscan[idx] + bscan[idx >> 8];
}

// ---------------- pack positions into u16-quantized 8B records --------------
__global__ void k_pack_pos(const float* __restrict__ r, ushort4* __restrict__ posq, int n) {
    int i = blockIdx.x * blockDim.x + threadIdx.x;
    if (i >= n) return;
    float x = r[3 * i], y = r[3 * i + 1], z = r[3 * i + 2];
    ushort4 q;
    q.x = (unsigned short)fminf(x * 65536.0f, 65535.0f);
    q.y = (unsigned short)fminf(y * 65536.0f, 65535.0f);
    q.z = (unsigned short)fminf(z * 65536.0f, 65535.0f);
    q.w = 0;
    posq[i] = q;
}

// ---------------- level-1 histogram by j-slice ----------------
__global__ void k_hist1(const int* __restrict__ j_s, int* __restrict__ ghist,
                        int nbA, int nsl, int E) {
    __shared__ int h[64];
    int t = threadIdx.x, blk = blockIdx.x;
    if (t < 64) h[t] = 0;
    __syncthreads();
    int base = blk * CH;
    int end = min(base + CH, E);
    for (int kb = base; kb < end; kb += 256 * 4) {
        int jv[4];
#pragma unroll
        for (int b = 0; b < 4; b++) {
            int k = kb + b * 256 + t;
            jv[b] = (k < end) ? j_s[k] : -1;
        }
#pragma unroll
        for (int b = 0; b < 4; b++)
            if (jv[b] >= 0) atomicAdd(&h[jv[b] >> JS_SH], 1);
    }
    __syncthreads();
    if (t < nsl) ghist[t * nbA + blk] = h[t];
}

// ---------------- 2-kernel scan (verified pattern) ----------------
__global__ void k_scan_block(const int* __restrict__ in, int* __restrict__ out,
                             int* __restrict__ bsum, int m) {
    __shared__ int s[256];
    int t = threadIdx.x;
    int i = blockIdx.x * 256 + t;
    int x = (i < m) ? in[i] : 0;
    s[t] = x;
    __syncthreads();
    for (int d = 1; d < 256; d <<= 1) {
        int v = (t >= d) ? s[t - d] : 0;
        __syncthreads();
        s[t] += v;
        __syncthreads();
    }
    if (i < m) out[i] = s[t] - x;            // block-local exclusive
    if (t == 255) bsum[blockIdx.x] = s[255];
}

__global__ void k_scan_bsums(const int* __restrict__ bsum, int* __restrict__ bscan, int nb) {
    __shared__ int s[512];
    __shared__ int carry;
    int t = threadIdx.x;
    if (t == 0) carry = 0;
    __syncthreads();
    for (int base = 0; base < nb; base += 512) {
        int i = base + t;
        int x = (i < nb) ? bsum[i] : 0;
        s[t] = x;
        __syncthreads();
        for (int d = 1; d < 512; d <<= 1) {
            int v = (t >= d) ? s[t - d] : 0;
            __syncthreads();
            s[t] += v;
            __syncthreads();
        }
        if (i < nb) bscan[i] = s[t] - x + carry;
        __syncthreads();
        if (t == 511) carry += s[511];
        __syncthreads();
    }
}

// ---------------- level-1 split: bin by j-slice, payload (i<<12 | j&4095) --
__global__ void k_split1(const int* __restrict__ i_s, const int* __restrict__ j_s,
                         const int* __restrict__ ghist, const int* __restrict__ gscan,
                         const int* __restrict__ bscan, int* __restrict__ pairs1,
                         int nbA, int nsl, int E) {
    __shared__ int lofs[64];
    __shared__ int ldelta[64];
    __shared__ int stage[CH];
    __shared__ unsigned short binof[CH];
    int t = threadIdx.x, blk = blockIdx.x;
    int base = blk * CH;
    int end = min(base + CH, E);
    int cnt = end - base;

    if (t < 64) {
        int h0 = (t < nsl) ? ghist[t * nbA + blk] : 0;
        lofs[t] = h0;
    }
    __syncthreads();
    if (t == 0) {                              // tiny serial scan of <=64 bins
        int run = 0;
        for (int b = 0; b < nsl; b++) {
            int h = lofs[b];
            lofs[b] = run;                     // exclusive
            ldelta[b] = scanned(gscan, bscan, b * nbA + blk) - run;
            run += h;
        }
    }
    __syncthreads();

    for (int kb = base; kb < end; kb += 256 * 4) {
        int iv[4], jv[4];
#pragma unroll
        for (int b = 0; b < 4; b++) {
            int k = kb + b * 256 + t;
            iv[b] = (k < end) ? i_s[k] : -1;
            jv[b] = (k < end) ? j_s[k] : 0;
        }
#pragma unroll
        for (int b = 0; b < 4; b++) {
            if (iv[b] < 0) continue;
            int bin = jv[b] >> JS_SH;
            int pos = atomicAdd(&lofs[bin], 1);
            stage[pos] = (iv[b] << JS_SH) | (jv[b] & (JSLICE - 1));
            binof[pos] = (unsigned short)bin;
        }
    }
    __syncthreads();
    for (int x = t; x < cnt; x += 256)
        pairs1[x + ldelta[binof[x]]] = stage[x];
}

// ---------------- level-2 histogram: per (slice, chunk) count i-bins -------
__global__ void k_hist2(const int* __restrict__ pairs1, const int* __restrict__ gscan1,
                        const int* __restrict__ bscan1, int* __restrict__ ghist2,
                        int nbA, int nsl, int nbin, int E) {
    __shared__ int h[256];
    int t = threadIdx.x;
    int s = blockIdx.x / C2MAX, c = blockIdx.x % C2MAX;
    h[t] = 0;
    __syncthreads();
    int start = scanned(gscan1, bscan1, s * nbA);
    int end = (s + 1 < nsl) ? scanned(gscan1, bscan1, (s + 1) * nbA) : E;
    int a0 = start + c * CH, a1 = min(a0 + CH, end);
    for (int kb = a0; kb < a1; kb += 256 * 4) {
        int pv[4];
#pragma unroll
        for (int b = 0; b < 4; b++) {
            int k = kb + b * 256 + t;
            pv[b] = (k < a1) ? pairs1[k] : -1;
        }
#pragma unroll
        for (int b = 0; b < 4; b++)
            if (pv[b] >= 0) atomicAdd(&h[pv[b] >> (JS_SH + IB_SH)], 1);
    }
    __syncthreads();
    if (t < nbin) ghist2[(s * nbin + t) * C2MAX + c] = h[t];
}

// ---------------- level-2 split: per-slice bin by i-bin --------------------
__global__ void k_split2(const int* __restrict__ pairs1, const int* __restrict__ ghist2,
                         const int* __restrict__ gscan2, const int* __restrict__ bscan2,
                         const int* __restrict__ gscan1, const int* __restrict__ bscan1,
                         int* __restrict__ pairs2, int nbA, int nsl, int nbin, int E) {
    __shared__ int lofs[256];
    __shared__ int ldelta[256];
    __shared__ int stage[CH];
    __shared__ unsigned short binof[CH];
    int t = threadIdx.x;
    int s = blockIdx.x / C2MAX, c = blockIdx.x % C2MAX;
    int start = scanned(gscan1, bscan1, s * nbA);
    int end = (s + 1 < nsl) ? scanned(gscan1, bscan1, (s + 1) * nbA) : E;
    int a0 = start + c * CH, a1 = min(a0 + CH, end);
    int cnt = max(a1 - a0, 0);

    int h0 = (t < nbin) ? ghist2[(s * nbin + t) * C2MAX + c] : 0;
    lofs[t] = h0;
    __syncthreads();
    for (int d = 1; d < 256; d <<= 1) {        // inclusive scan of 256
        int v = (t >= d) ? lofs[t - d] : 0;
        __syncthreads();
        lofs[t] += v;
        __syncthreads();
    }
    int e0 = lofs[t] - h0;                     // exclusive
    __syncthreads();
    lofs[t] = e0;                              // cursor
    if (t < nbin) ldelta[t] = scanned(gscan2, bscan2, (s * nbin + t) * C2MAX + c) - e0;
    __syncthreads();

    for (int kb = a0; kb < a1; kb += 256 * 4) {
        int pv[4];
#pragma unroll
        for (int b = 0; b < 4; b++) {
            int k = kb + b * 256 + t;
            pv[b] = (k < a1) ? pairs1[k] : -1;
        }
#pragma unroll
        for (int b = 0; b < 4; b++) {
            if (pv[b] < 0) continue;
            int bin = pv[b] >> (JS_SH + IB_SH);
            int pos = atomicAdd(&lofs[bin], 1);
            stage[pos] = pv[b];
            binof[pos] = (unsigned short)bin;
        }
    }
    __syncthreads();
    for (int x = t; x < cnt; x += 256)
        pairs2[x + ldelta[binof[x]]] = stage[x];
}

// ---------------- pass 1: density + aux — 39KB LDS, 4 blocks/CU ------------
__global__ void __launch_bounds__(PB, 8)
k_pass1(const ushort4* __restrict__ posq, const int* __restrict__ pairs2,
        const int* __restrict__ gscan2, const int* __restrict__ bscan2,
        float* __restrict__ part_rho, hf4* __restrict__ aux,
        int n, int E, int nsl, int nbin, int nbg, int nk) {
    __shared__ ushort4 sjp[JSLICE];            // 32 KB
    __shared__ ushort4 sip[IBSZ];              // 4 KB
    __shared__ float srho[IBSZ];               // 2 KB
    __shared__ int sbin[GBIN + 1];
    int t = threadIdx.x;
    int s = blockIdx.x / nbg, g = blockIdx.x % nbg;
    int j0 = s << JS_SH;
    for (int idx = t; idx < JSLICE; idx += PB) {
        int jg = j0 + idx;
        sjp[idx] = (jg < n) ? posq[jg] : make_ushort4(0, 0, 0, 0);
    }
    int b0 = g * GBIN, b1 = min(b0 + GBIN, nbin);
    if (t <= GBIN) {                           // 9 parallel range fetches
        int lin = min(s * nbin + b0 + t, nk);
        sbin[t] = (lin < nk) ? scanned(gscan2, bscan2, lin * C2MAX) : E;
    }
    for (int bin = b0; bin < b1; bin++) {
        int i0 = bin << IB_SH;
        {
            int ig = i0 + t;                   // PB==IBSZ: all threads stage
            sip[t] = (ig < n) ? posq[ig] : make_ushort4(0, 0, 0, 0);
            srho[t] = 0.f;
        }
        __syncthreads();                       // stage visible (covers sjp 1st)
        int ks = sbin[bin - b0], ke = sbin[bin - b0 + 1];
        for (int kb = ks; kb < ke; kb += PB * 2) {
            int pr[2], kk[2];
            bool live[2];
#pragma unroll
            for (int b = 0; b < 2; b++) {
                int k = kb + b * PB + t;
                live[b] = (k < ke);
                kk[b] = live[b] ? k : ke - 1;
                pr[b] = nt_load_i(&pairs2[kk[b]]);
            }
            ushort4 pj[2], pi[2];
#pragma unroll
            for (int b = 0; b < 2; b++) {
                pj[b] = sjp[pr[b] & (JSLICE - 1)];
                pi[b] = sip[(pr[b] >> JS_SH) & (IBSZ - 1)];
            }
#pragma unroll
            for (int b = 0; b < 2; b++) {
                float dx = (float)((int)pi[b].x - (int)pj[b].x) * kInvQ;
                float dy = (float)((int)pi[b].y - (int)pj[b].y) * kInvQ;
                float dz = (float)((int)pi[b].z - (int)pj[b].z) * kInvQ;
                float d = sqrtf(dx * dx + dy * dy + dz * dz);
                float t1 = fmaxf(1.f - d, 0.f);
                float t2 = fmaxf(2.f - d, 0.f);
                float t3 = fmaxf(3.f - d, 0.f);
                float w = kSigma * (pow5f(t3) - 6.f * pow5f(t2) + 15.f * pow5f(t1));
                hf4 h;
                h.x = (_Float16)dx; h.y = (_Float16)dy;
                h.z = (_Float16)dz; h.w = (_Float16)d;
                if (live[b]) {
                    atomicAdd(&srho[(pr[b] >> JS_SH) & (IBSZ - 1)], w);
                    nt_store_h4(&aux[kk[b]], h);           // coalesced 8B
                }
            }
        }
        __syncthreads();                       // processing done
        {
            int ig = i0 + t;
            if (ig < n) nt_store_f(&part_rho[(size_t)s * n + ig], srho[t]);
        }
        // next-iter stage of sip[t]/srho[t] is by same thread t: safe, no bar
    }
}

// ---------------- reduce rho partials; pack {v,p} f16; state out -----------
__global__ void k_reduce_rho(const float* __restrict__ part_rho,
                             const float* __restrict__ v,
                             hf4* __restrict__ vpq, float* __restrict__ out,
                             int n, int nsl) {
    int i = blockIdx.x * blockDim.x + threadIdx.x;
    if (i >= n) return;
    float rh = 0.f;
    for (int s = 0; s < nsl; s++) rh += nt_load_f(&part_rho[(size_t)s * n + i]);
    float pp = kPRef * (rh - 1.0f);
    hf4 h;
    h.x = (_Float16)v[3 * i];
    h.y = (_Float16)v[3 * i + 1];
    h.z = (_Float16)v[3 * i + 2];
    h.w = (_Float16)pp;
    vpq[i] = h;
    float* o = out + (size_t)i * 8;
    o[0] = rh;
    o[1] = pp;
    o[5] = 0.f; o[6] = 0.f; o[7] = 0.f;       // dvdt == 0 exactly
}

// ---------------- pass 2: acceleration — 43KB LDS, 3 blocks/CU -------------
// no positions needed: aux{dx,dy,dz,d} streamed per edge.
__global__ void __launch_bounds__(PB, 6)
k_pass2(const hf4* __restrict__ vpq, const int* __restrict__ pairs2,
        const hf4* __restrict__ aux, const int* __restrict__ gscan2,
        const int* __restrict__ bscan2, float* __restrict__ pax,
        float* __restrict__ pay, float* __restrict__ paz,
        int n, int E, int nsl, int nbin, int nbg, int nk) {
    __shared__ hf4 sjv[JSLICE];                // 32 KB {vx,vy,vz,p}
    __shared__ hf4 siv[IBSZ];                  // 4 KB
    __shared__ float sax[IBSZ], say[IBSZ], saz[IBSZ];   // 6 KB
    __shared__ int sbin[GBIN + 1];
    int t = threadIdx.x;
    int s = blockIdx.x / nbg, g = blockIdx.x % nbg;
    int j0 = s << JS_SH;
    for (int idx = t; idx < JSLICE; idx += PB) {
        int jg = j0 + idx;
        sjv[idx] = (jg < n) ? vpq[jg] : hf4{0, 0, 0, 0};
    }
    int b0 = g * GBIN, b1 = min(b0 + GBIN, nbin);
    if (t <= GBIN) {
        int lin = min(s * nbin + b0 + t, nk);
        sbin[t] = (lin < nk) ? scanned(gscan2, bscan2, lin * C2MAX) : E;
    }
    for (int bin = b0; bin < b1; bin++) {
        int i0 = bin << IB_SH;
        {
            int ig = i0 + t;
            siv[t] = (ig < n) ? vpq[ig] : hf4{0, 0, 0, 0};
            sax[t] = 0.f; say[t] = 0.f; saz[t] = 0.f;
        }
        __syncthreads();
        int ks = sbin[bin - b0], ke = sbin[bin - b0 + 1];
        for (int kb = ks; kb < ke; kb += PB * 2) {
            int pr[2], kk[2];
            bool live[2];
            hf4 hx[2];
#pragma unroll
            for (int b = 0; b < 2; b++) {
                int k = kb + b * PB + t;
                live[b] = (k < ke);
                kk[b] = live[b] ? k : ke - 1;
                pr[b] = nt_load_i(&pairs2[kk[b]]);
                hx[b] = nt_load_h4(&aux[kk[b]]);
            }
            hf4 vj[2], vi[2];
#pragma unroll
            for (int b = 0; b < 2; b++) {
                vj[b] = sjv[pr[b] & (JSLICE - 1)];
                vi[b] = siv[(pr[b] >> JS_SH) & (IBSZ - 1)];
            }
#pragma unroll
            for (int b = 0; b < 2; b++) {
                int il = (pr[b] >> JS_SH) & (IBSZ - 1);
                float dx = (float)hx[b].x, dy = (float)hx[b].y, dz = (float)hx[b].z;
                float d = (float)hx[b].w;
                float p_i = (float)vi[b].w, p_j = (float)vj[b].w;
                float rho_i = p_i * 0.01f + 1.0f;
                float rho_j = p_j * 0.01f + 1.0f;
                float t1 = fmaxf(1.f - d, 0.f);
                float t2 = fmaxf(2.f - d, 0.f);
                float t3 = fmaxf(3.f - d, 0.f);
                float gw = kSigma * (-5.f * pow4f(t3) + 30.f * pow4f(t2) - 75.f * pow4f(t1));
                float inv_i = 1.0f / rho_i, inv_j = 1.0f / rho_j;
                float c = (inv_i * inv_i + inv_j * inv_j) * gw / (d + kEps);
                float p_ij = (rho_j * p_i + rho_i * p_j) / (rho_i + rho_j);
                if (live[b]) {
                    atomicAdd(&sax[il], c * (kEta * ((float)vi[b].x - (float)vj[b].x) - p_ij * dx));
                    atomicAdd(&say[il], c * (kEta * ((float)vi[b].y - (float)vj[b].y) - p_ij * dy));
                    atomicAdd(&saz[il], c * (kEta * ((float)vi[b].z - (float)vj[b].z) - p_ij * dz));
                }
            }
        }
        __syncthreads();
        {
            int ig = i0 + t;
            if (ig < n) {
                nt_store_f(&pax[(size_t)s * n + ig], sax[t]);
                nt_store_f(&pay[(size_t)s * n + ig], say[t]);
                nt_store_f(&paz[(size_t)s * n + ig], saz[t]);
            }
        }
    }
}

// ---------------- reduce acc partials ----------------
__global__ void k_reduce_acc(const float* __restrict__ pax, const float* __restrict__ pay,
                             const float* __restrict__ paz, float* __restrict__ out,
                             int n, int nsl) {
    int i = blockIdx.x * blockDim.x + threadIdx.x;
    if (i >= n) return;
    float ax = 0.f, ay = 0.f, az = 0.f;
    for (int s = 0; s < nsl; s++) {
        ax += nt_load_f(&pax[(size_t)s * n + i]);
        ay += nt_load_f(&pay[(size_t)s * n + i]);
        az += nt_load_f(&paz[(size_t)s * n + i]);
    }
    float* o = out + (size_t)i * 8 + 2;
    o[0] = ax; o[1] = ay; o[2] = az;
}

// ---------------- launch ----------------
static inline char* wcarve(char*& ws, size_t bytes) {
    char* p = ws;
    ws += (bytes + 255) & ~(size_t)255;
    return p;
}

extern "C" void kernel_launch(void* const* d_in, const int* in_sizes, int n_in,
                              void* d_out, int out_size, void* d_ws, size_t ws_size,
                              hipStream_t stream) {
    const float* r = (const float*)d_in[0];
    const float* v = (const float*)d_in[1];
    const int* i_s = (const int*)d_in[2];
    const int* j_s = (const int*)d_in[3];
    int n = in_sizes[0] / 3;
    int E = in_sizes[2];
    float* out = (float*)d_out;

    int nsl  = ((n - 1) >> JS_SH) + 1;                 // 25 j-slices
    int nbin = ((n - 1) >> IB_SH) + 1;                 // 196 i-bins
    int nk   = nsl * nbin;                             // 4900 keys
    int nbg  = (nbin + GBIN - 1) / GBIN;               // 25 bin-groups
    int nbA  = (E + CH - 1) / CH;                      // 782 chunks
    int m1   = nsl * nbA;                              // level-1 scan length
    int m2   = nk * C2MAX;                             // level-2 scan length
    int nb1  = (m1 + 255) / 256;
    int nb2  = (m2 + 255) / 256;

    char* ws = (char*)d_ws;
    ushort4* posq   = (ushort4*)wcarve(ws, (size_t)n * 8);
    hf4*     vpq    = (hf4*)wcarve(ws, (size_t)n * 8);
    int*     ghist1 = (int*)wcarve(ws, (size_t)m1 * 4);
    int*     gscan1 = (int*)wcarve(ws, (size_t)m1 * 4);
    int*     bsum1  = (int*)wcarve(ws, (size_t)nb1 * 4);
    int*     bscan1 = (int*)wcarve(ws, (size_t)nb1 * 4);
    int*     pairs1 = (int*)wcarve(ws, (size_t)E * 4);
    int*     ghist2 = (int*)wcarve(ws, (size_t)m2 * 4);
    int*     gscan2 = (int*)wcarve(ws, (size_t)m2 * 4);
    int*     bsum2  = (int*)wcarve(ws, (size_t)nb2 * 4);
    int*     bscan2 = (int*)wcarve(ws, (size_t)nb2 * 4);
    int*     pairs2 = (int*)wcarve(ws, (size_t)E * 4);
    hf4*     aux    = (hf4*)wcarve(ws, (size_t)E * 8);
    float*   part_rho = (float*)wcarve(ws, (size_t)nsl * n * 4);
    float*   pax    = (float*)wcarve(ws, (size_t)nsl * n * 4);
    float*   pay    = (float*)wcarve(ws, (size_t)nsl * n * 4);
    float*   paz    = (float*)wcarve(ws, (size_t)nsl * n * 4);

    const int bs = 256;
    int gn = (n + bs - 1) / bs;

    k_pack_pos<<<gn, bs, 0, stream>>>(r, posq, n);
    k_hist1<<<nbA, 256, 0, stream>>>(j_s, ghist1, nbA, nsl, E);
    k_scan_block<<<nb1, 256, 0, stream>>>(ghist1, gscan1, bsum1, m1);
    k_scan_bsums<<<1, 512, 0, stream>>>(bsum1, bscan1, nb1);
    k_split1<<<nbA, 256, 0, stream>>>(i_s, j_s, ghist1, gscan1, bscan1, pairs1, nbA, nsl, E);
    k_hist2<<<nsl * C2MAX, 256, 0, stream>>>(pairs1, gscan1, bscan1, ghist2, nbA, nsl, nbin, E);
    k_scan_block<<<nb2, 256, 0, stream>>>(ghist2, gscan2, bsum2, m2);
    k_scan_bsums<<<1, 512, 0, stream>>>(bsum2, bscan2, nb2);
    k_split2<<<nsl * C2MAX, 256, 0, stream>>>(pairs1, ghist2, gscan2, bscan2,
                                              gscan1, bscan1, pairs2, nbA, nsl, nbin, E);
    k_pass1<<<nsl * nbg, PB, 0, stream>>>(posq, pairs2, gscan2, bscan2, part_rho, aux,
                                          n, E, nsl, nbin, nbg, nk);
    k_reduce_rho<<<gn, bs, 0, stream>>>(part_rho, v, vpq, out, n, nsl);
    k_pass2<<<nsl * nbg, PB, 0, stream>>>(vpq, pairs2, aux, gscan2, bscan2,
                                          pax, pay, paz, n, E, nsl, nbin, nbg, nk);
    k_reduce_acc<<<gn, bs, 0, stream>>>(pax, pay, paz, out, n, nsl);
}